// Round 2
// baseline (716.082 us; speedup 1.0000x reference)
//
#include <hip/hip_runtime.h>
#include <hip/hip_bf16.h>

#define T_IN   16
#define T_OUT  25
#define BHERO  4096
#define K_NBR  32
#define N_NBR  (BHERO * K_NBR)
#define ENC    64
#define DEC    128
#define DYN    32
#define EMB    32
#define HPB    4          // heroes per decoder workgroup

__device__ __forceinline__ float lrelu(float x) { return x >= 0.f ? x : 0.1f * x; }
__device__ __forceinline__ float sigm(float x)  { return 1.f / (1.f + __expf(-x)); }
__device__ __forceinline__ float tanh_f(float x) {
    float e = __expf(-2.f * fabsf(x));        // in (0,1], no overflow
    float t = (1.f - e) / (1.f + e);
    return x >= 0.f ? t : -t;
}

// ---------------- Kernel 1: ego history encoder (LSTM hidden=64) ----------------
// One workgroup (256 threads) per hero. Thread r owns gate row r:
// Wih_e[r,0:32] + Whh_e[r,0:64] live in registers; h lives in LDS (broadcast reads).
// __launch_bounds__(256,2): 4 waves/WG = 1 wave/EU minimum anyway, but the explicit
// min-2 bound caps VGPR at 256 — ~120 needed, so no spill and 2 WGs/CU possible.
__global__ __launch_bounds__(256, 2) void ego_encoder_kernel(
    const float* __restrict__ hist,
    const float* __restrict__ Wip,  const float* __restrict__ bip,
    const float* __restrict__ Wih,  const float* __restrict__ Whh,
    const float* __restrict__ bih,  const float* __restrict__ bhh,
    const float* __restrict__ Wdyn, const float* __restrict__ bdyn,
    float* __restrict__ enc_out)                    // [BHERO][64], writes cols 0..31
{
    const int b = blockIdx.x;
    const int r = threadIdx.x;                      // gate row 0..255 (i,f,g,o blocks of 64)

    __shared__ __align__(16) float x_s[EMB];
    __shared__ __align__(16) float h_s[ENC];
    __shared__ float g_s[4 * ENC];

    float wih[EMB];
    {
        const float4* w4 = (const float4*)(Wih + (size_t)r * EMB);
        #pragma unroll
        for (int j = 0; j < EMB / 4; ++j) {
            float4 w = w4[j];
            wih[4*j+0] = w.x; wih[4*j+1] = w.y; wih[4*j+2] = w.z; wih[4*j+3] = w.w;
        }
    }
    float whh[ENC];
    {
        const float4* w4 = (const float4*)(Whh + (size_t)r * ENC);
        #pragma unroll
        for (int j = 0; j < ENC / 4; ++j) {
            float4 w = w4[j];
            whh[4*j+0] = w.x; whh[4*j+1] = w.y; whh[4*j+2] = w.z; whh[4*j+3] = w.w;
        }
    }
    const float bias = bih[r] + bhh[r];

    float wip0 = 0.f, wip1 = 0.f, bipv = 0.f;
    if (r < EMB) { wip0 = Wip[2*r]; wip1 = Wip[2*r + 1]; bipv = bip[r]; }
    if (r < ENC) h_s[r] = 0.f;
    float c = 0.f;                                   // cell state (threads r<64 only)
    __syncthreads();

    for (int t = 0; t < T_IN; ++t) {
        if (r < EMB) {
            float h0 = hist[((size_t)t * BHERO + b) * 2 + 0];
            float h1 = hist[((size_t)t * BHERO + b) * 2 + 1];
            x_s[r] = lrelu(fmaf(h0, wip0, fmaf(h1, wip1, bipv)));
        }
        __syncthreads();
        float a0 = 0.f, a1 = 0.f, a2 = 0.f, a3 = 0.f;
        #pragma unroll
        for (int j = 0; j < EMB; j += 4) {
            float4 xv = *(const float4*)&x_s[j];
            a0 = fmaf(wih[j+0], xv.x, a0);
            a1 = fmaf(wih[j+1], xv.y, a1);
            a2 = fmaf(wih[j+2], xv.z, a2);
            a3 = fmaf(wih[j+3], xv.w, a3);
        }
        #pragma unroll
        for (int j = 0; j < ENC; j += 4) {
            float4 hv = *(const float4*)&h_s[j];
            a0 = fmaf(whh[j+0], hv.x, a0);
            a1 = fmaf(whh[j+1], hv.y, a1);
            a2 = fmaf(whh[j+2], hv.z, a2);
            a3 = fmaf(whh[j+3], hv.w, a3);
        }
        g_s[r] = bias + ((a0 + a1) + (a2 + a3));
        __syncthreads();
        if (r < ENC) {
            float ig = g_s[r], fg = g_s[ENC + r], gg = g_s[2*ENC + r], og = g_s[3*ENC + r];
            c = sigm(fg) * c + sigm(ig) * tanh_f(gg);
            h_s[r] = sigm(og) * tanh_f(c);
        }
        __syncthreads();
    }

    // hist_e = lrelu(h_enc @ Wdyn.T + bdyn) -> enc_out cols 0..31
    if (r < DYN) {
        float a0 = 0.f, a1 = 0.f, a2 = 0.f, a3 = 0.f;
        #pragma unroll
        for (int j = 0; j < ENC; j += 4) {
            a0 = fmaf(Wdyn[r*ENC + j + 0], h_s[j + 0], a0);
            a1 = fmaf(Wdyn[r*ENC + j + 1], h_s[j + 1], a1);
            a2 = fmaf(Wdyn[r*ENC + j + 2], h_s[j + 2], a2);
            a3 = fmaf(Wdyn[r*ENC + j + 3], h_s[j + 3], a3);
        }
        enc_out[(size_t)b * (2*DYN) + r] = lrelu(bdyn[r] + ((a0 + a1) + (a2 + a3)));
    }
}

// ---------------- Kernel 2: neighbor scene (rela proj + segment max + proj) ----------------
// One workgroup (64 threads = 1 wave) per hero.
__global__ __launch_bounds__(64) void nbr_scene_kernel(
    const float* __restrict__ hist, const float* __restrict__ nbrs,
    const int*   __restrict__ seg,
    const float* __restrict__ Wnbr, const float* __restrict__ bnbr,
    const float* __restrict__ Wdyn, const float* __restrict__ bdyn,
    float* __restrict__ enc_out)                    // [BHERO][64], writes cols 32..63
{
    const int b   = blockIdx.x;
    const int tid = threadIdx.x;                    // 0..63

    __shared__ float rela_s[K_NBR][2 * T_IN + 1];   // +1 pad: kills 32-way write conflict
    __shared__ float scene_s[ENC];

    const int n0 = b * K_NBR;
    const int k  = tid >> 1, cch = tid & 1;
    const int hb = seg[n0 + k];                     // hero id via segment_ids (faithful gather)
    for (int t = 0; t < T_IN; ++t) {
        float hv = hist[((size_t)t * BHERO + hb) * 2 + cch];
        float nv = nbrs[((size_t)t * N_NBR + n0 + k) * 2 + cch];
        rela_s[k][2*t + cch] = hv - nv;
    }
    __syncthreads();

    float w[2 * T_IN];
    #pragma unroll
    for (int j = 0; j < 2 * T_IN; ++j) w[j] = Wnbr[tid * (2*T_IN) + j];
    const float bn = bnbr[tid];

    float m = -1e30f;
    for (int kk = 0; kk < K_NBR; ++kk) {
        float a0 = 0.f, a1 = 0.f, a2 = 0.f, a3 = 0.f;
        #pragma unroll
        for (int j = 0; j < 2 * T_IN; j += 4) {
            a0 = fmaf(w[j+0], rela_s[kk][j+0], a0);
            a1 = fmaf(w[j+1], rela_s[kk][j+1], a1);
            a2 = fmaf(w[j+2], rela_s[kk][j+2], a2);
            a3 = fmaf(w[j+3], rela_s[kk][j+3], a3);
        }
        m = fmaxf(m, lrelu(bn + ((a0 + a1) + (a2 + a3))));
    }
    scene_s[tid] = m;
    __syncthreads();

    if (tid < DYN) {
        float a0 = 0.f, a1 = 0.f, a2 = 0.f, a3 = 0.f;
        #pragma unroll
        for (int j = 0; j < ENC; j += 4) {
            a0 = fmaf(Wdyn[tid*ENC + j + 0], scene_s[j + 0], a0);
            a1 = fmaf(Wdyn[tid*ENC + j + 1], scene_s[j + 1], a1);
            a2 = fmaf(Wdyn[tid*ENC + j + 2], scene_s[j + 2], a2);
            a3 = fmaf(Wdyn[tid*ENC + j + 3], scene_s[j + 3], a3);
        }
        enc_out[(size_t)b * (2*DYN) + DYN + tid] = lrelu(bdyn[tid] + ((a0 + a1) + (a2 + a3)));
    }
}

// ---------------- Kernel 3: decoder LSTM (hidden=128, 25 steps) + output head ----------------
// One workgroup (512 threads) per FOUR heroes; thread r owns gate row r (Whh_d row in
// 128 registers, reused for all 4 heroes). Input is constant over steps -> xW precomputed.
// __launch_bounds__(512, 2): 8 waves/WG = 2 waves/EU -> VGPR cap 256; kernel needs
// ~170 (128 whh + 16 acc + misc) -> NO SPILL (round-1 ran at VGPR=128 and spilled
// 470 MB/dispatch of scratch traffic to HBM).
__global__ __launch_bounds__(512, 2) void decoder_kernel(
    const float* __restrict__ enc,                  // [BHERO][64]
    const float* __restrict__ Wih,  const float* __restrict__ Whh,
    const float* __restrict__ bih,  const float* __restrict__ bhh,
    const float* __restrict__ Wop,  const float* __restrict__ bop,
    float* __restrict__ fut)                        // [T_OUT][BHERO][2]
{
    const int b0 = blockIdx.x * HPB;
    const int r  = threadIdx.x;                     // 0..511, gate row

    __shared__ __align__(16) float h_s[HPB][DEC];
    __shared__ float g_s[HPB][4 * DEC];
    __shared__ __align__(16) float enc_s[HPB][2 * DYN];
    __shared__ float red_s[8][2];                   // one slot per wave

    if (r < HPB * (2*DYN)) enc_s[r >> 6][r & 63] = enc[(size_t)b0 * (2*DYN) + r];
    if (r < HPB * DEC)     h_s[r >> 7][r & 127] = 0.f;
    __syncthreads();

    float whh[DEC];
    {
        const float4* w4 = (const float4*)(Whh + (size_t)r * DEC);
        #pragma unroll
        for (int j = 0; j < DEC / 4; ++j) {
            float4 w = w4[j];
            whh[4*j+0] = w.x; whh[4*j+1] = w.y; whh[4*j+2] = w.z; whh[4*j+3] = w.w;
        }
    }
    const float bsum = bih[r] + bhh[r];
    float xw[HPB];
    #pragma unroll
    for (int hh2 = 0; hh2 < HPB; ++hh2) xw[hh2] = bsum;
    {
        const float4* w4 = (const float4*)(Wih + (size_t)r * (2*DYN));
        #pragma unroll
        for (int j = 0; j < (2*DYN) / 4; ++j) {
            float4 w = w4[j];
            #pragma unroll
            for (int hh2 = 0; hh2 < HPB; ++hh2) {
                float4 e = *(const float4*)&enc_s[hh2][4*j];
                xw[hh2] += w.x*e.x + w.y*e.y + w.z*e.z + w.w*e.w;
            }
        }
    }

    const int hh = r >> 7, u = r & 127;             // this thread's (hero, unit) for nonlin
    float c = 0.f;
    const float wop0 = Wop[u];                      // Wop[0][u]
    const float wop1 = Wop[DEC + u];                // Wop[1][u]
    const float bop0 = bop[0], bop1 = bop[1];

    for (int t = 0; t < T_OUT; ++t) {
        float a[HPB][2];
        #pragma unroll
        for (int hh2 = 0; hh2 < HPB; ++hh2) { a[hh2][0] = 0.f; a[hh2][1] = 0.f; }
        #pragma unroll
        for (int j = 0; j < DEC; j += 4) {
            #pragma unroll
            for (int hh2 = 0; hh2 < HPB; ++hh2) {
                float4 hv = *(const float4*)&h_s[hh2][j];
                a[hh2][0] = fmaf(whh[j+0], hv.x, a[hh2][0]);
                a[hh2][1] = fmaf(whh[j+1], hv.y, a[hh2][1]);
                a[hh2][0] = fmaf(whh[j+2], hv.z, a[hh2][0]);
                a[hh2][1] = fmaf(whh[j+3], hv.w, a[hh2][1]);
            }
        }
        #pragma unroll
        for (int hh2 = 0; hh2 < HPB; ++hh2)
            g_s[hh2][r] = xw[hh2] + (a[hh2][0] + a[hh2][1]);
        __syncthreads();                            // g ready

        // nonlinearity: every thread handles one (hero, unit)
        float ig = g_s[hh][u], fg = g_s[hh][DEC + u];
        float gg = g_s[hh][2*DEC + u], og = g_s[hh][3*DEC + u];
        c = sigm(fg) * c + sigm(ig) * tanh_f(gg);
        float h = sigm(og) * tanh_f(c);
        h_s[hh][u] = h;
        // fused output head: shuffle-reduce h·Wop over the wave (wave w covers hero w>>1)
        float p0 = wop0 * h, p1 = wop1 * h;
        #pragma unroll
        for (int off = 32; off > 0; off >>= 1) {
            p0 += __shfl_down(p0, off);
            p1 += __shfl_down(p1, off);
        }
        if ((r & 63) == 0) { red_s[r >> 6][0] = p0; red_s[r >> 6][1] = p1; }
        __syncthreads();                            // h + red ready

        if (r < HPB) {
            float o0 = red_s[2*r][0] + red_s[2*r + 1][0] + bop0;
            float o1 = red_s[2*r][1] + red_s[2*r + 1][1] + bop1;
            float* dst = fut + ((size_t)t * BHERO + b0 + r) * 2;
            dst[0] = o0; dst[1] = o1;
            // no extra barrier: next iteration's red_s/h_s writes are ordered after
            // this read by the next iteration's g-ready __syncthreads().
        }
    }
}

extern "C" void kernel_launch(void* const* d_in, const int* in_sizes, int n_in,
                              void* d_out, int out_size, void* d_ws, size_t ws_size,
                              hipStream_t stream) {
    const float* hist  = (const float*)d_in[0];
    const float* nbrs  = (const float*)d_in[1];
    const float* Wip   = (const float*)d_in[2];
    const float* bip   = (const float*)d_in[3];
    const float* Wih_e = (const float*)d_in[4];
    const float* Whh_e = (const float*)d_in[5];
    const float* bih_e = (const float*)d_in[6];
    const float* bhh_e = (const float*)d_in[7];
    const float* Wdyn  = (const float*)d_in[8];
    const float* bdyn  = (const float*)d_in[9];
    const float* Wnbr  = (const float*)d_in[10];
    const float* bnbr  = (const float*)d_in[11];
    const float* Wih_d = (const float*)d_in[12];
    const float* Whh_d = (const float*)d_in[13];
    const float* bih_d = (const float*)d_in[14];
    const float* bhh_d = (const float*)d_in[15];
    const float* Wop   = (const float*)d_in[16];
    const float* bop   = (const float*)d_in[17];
    const int*   seg   = (const int*)d_in[18];

    float* fut    = (float*)d_out;
    float* enc_ws = (float*)d_ws;                   // [BHERO][64] = 1 MB scratch

    hipLaunchKernelGGL(ego_encoder_kernel, dim3(BHERO), dim3(256), 0, stream,
                       hist, Wip, bip, Wih_e, Whh_e, bih_e, bhh_e, Wdyn, bdyn, enc_ws);
    hipLaunchKernelGGL(nbr_scene_kernel, dim3(BHERO), dim3(64), 0, stream,
                       hist, nbrs, seg, Wnbr, bnbr, Wdyn, bdyn, enc_ws);
    hipLaunchKernelGGL(decoder_kernel, dim3(BHERO / HPB), dim3(512), 0, stream,
                       enc_ws, Wih_d, Whh_d, bih_d, bhh_d, Wop, bop, fut);
}

// Round 3
// 130.319 us; speedup vs baseline: 5.4948x; 5.4948x over previous
//
#include <hip/hip_runtime.h>
#include <hip/hip_bf16.h>

#define T_IN   16
#define T_OUT  25
#define BHERO  4096
#define K_NBR  32
#define N_NBR  (BHERO * K_NBR)
#define ENC    64
#define DEC    128
#define DYN    32
#define EMB    32

#define EROW   104        // encoder LDS row: [emb 32 | h 64] = 96 bf16, pad->104 (208B = 13*16B)
#define DROW   136        // decoder LDS row: 128 bf16, pad->136 (272B = 17*16B)

typedef __attribute__((ext_vector_type(8))) short bf16x8;   // 8 bf16 in 4 VGPRs
typedef __attribute__((ext_vector_type(4))) float f32x4;    // MFMA 16x16 C/D frag

__device__ __forceinline__ float lrelu(float x) { return x >= 0.f ? x : 0.1f * x; }
__device__ __forceinline__ float sigm(float x)  { return 1.f / (1.f + __expf(-x)); }
__device__ __forceinline__ float tanh_f(float x) {
    float e = __expf(-2.f * fabsf(x));
    float t = (1.f - e) / (1.f + e);
    return x >= 0.f ? t : -t;
}
__device__ __forceinline__ short f2bf(float x) {            // f32 -> bf16, round-nearest-even
    unsigned u = __float_as_uint(x);
    return (short)((u + 0x7FFFu + ((u >> 16) & 1u)) >> 16);
}
__device__ __forceinline__ float bf2f(short s) {
    return __uint_as_float(((unsigned)(unsigned short)s) << 16);
}

// ---------------- Kernel 1: ego encoder, MFMA version ----------------
// 256 threads (4 waves) per 16 heroes. Wave w owns units w*16..w*16+15 across all 4
// gate blocks (i,f,g,o). K = 96 = [emb 32 | h 64], split in 3 chunks of 32.
// k-slot mapping (uniform across lanes, identical for A and B -> layout-safe):
//   chunk c, lane-group lg=l>>4, elem e: k = 32c + 8*lg + e.
__global__ __launch_bounds__(256, 2) void ego_encoder_mfma(
    const float* __restrict__ hist,
    const float* __restrict__ Wip,  const float* __restrict__ bip,
    const float* __restrict__ Wih,  const float* __restrict__ Whh,
    const float* __restrict__ bih,  const float* __restrict__ bhh,
    const float* __restrict__ Wdyn, const float* __restrict__ bdyn,
    float* __restrict__ enc_out)                 // [BHERO][64], cols 0..31
{
    const int b0  = blockIdx.x * 16;
    const int tid = threadIdx.x;
    const int w = tid >> 6, l = tid & 63, r = l & 15, lg = l >> 4;

    __shared__ __align__(16) short xh[16][EROW];  // row m: [emb(32) | h(64) | pad]

    // zero h region (cols 32..95)
    for (int i = tid; i < 16 * 64; i += 256) xh[i >> 6][32 + (i & 63)] = 0;

    // B-frags in registers: 4 gate tiles x 3 k-chunks
    bf16x8 Bf[4][3];
    float  biasj[4];
    #pragma unroll
    for (int j = 0; j < 4; ++j) {
        const int col = j * ENC + w * 16 + r;      // gate row (output col)
        biasj[j] = bih[col] + bhh[col];
        #pragma unroll
        for (int c = 0; c < 3; ++c) {
            const float* src = (c == 0) ? (Wih + (size_t)col * EMB + 8 * lg)
                                        : (Whh + (size_t)col * ENC + (c - 1) * 32 + 8 * lg);
            float4 f0 = *(const float4*)src;
            float4 f1 = *(const float4*)(src + 4);
            bf16x8 bb;
            bb[0]=f2bf(f0.x); bb[1]=f2bf(f0.y); bb[2]=f2bf(f0.z); bb[3]=f2bf(f0.w);
            bb[4]=f2bf(f1.x); bb[5]=f2bf(f1.y); bb[6]=f2bf(f1.z); bb[7]=f2bf(f1.w);
            Bf[j][c] = bb;
        }
    }

    f32x4 cst = {0.f, 0.f, 0.f, 0.f};              // cell state: hero 4*lg+q, unit w*16+r

    for (int t = 0; t < T_IN; ++t) {
        // emb = lrelu(hist @ Wip^T + bip): 512 slots, 2 per thread
        #pragma unroll
        for (int s2 = 0; s2 < 2; ++s2) {
            int s = tid + 256 * s2;
            int j = s >> 4, m = s & 15;
            float h0 = hist[((size_t)t * BHERO + b0 + m) * 2 + 0];
            float h1 = hist[((size_t)t * BHERO + b0 + m) * 2 + 1];
            xh[m][j] = f2bf(lrelu(h0 * Wip[2*j] + h1 * Wip[2*j + 1] + bip[j]));
        }
        __syncthreads();                            // emb + h ready

        bf16x8 a0 = *(const bf16x8*)&xh[r][(0 + lg) * 8];
        bf16x8 a1 = *(const bf16x8*)&xh[r][(4 + lg) * 8];
        bf16x8 a2 = *(const bf16x8*)&xh[r][(8 + lg) * 8];

        f32x4 acc[4];
        #pragma unroll
        for (int j = 0; j < 4; ++j) {
            acc[j] = (f32x4){biasj[j], biasj[j], biasj[j], biasj[j]};
            acc[j] = __builtin_amdgcn_mfma_f32_16x16x32_bf16(a0, Bf[j][0], acc[j], 0, 0, 0);
            acc[j] = __builtin_amdgcn_mfma_f32_16x16x32_bf16(a1, Bf[j][1], acc[j], 0, 0, 0);
            acc[j] = __builtin_amdgcn_mfma_f32_16x16x32_bf16(a2, Bf[j][2], acc[j], 0, 0, 0);
        }
        float hq[4];
        #pragma unroll
        for (int q = 0; q < 4; ++q) {
            float ig = acc[0][q], fg = acc[1][q], gg = acc[2][q], og = acc[3][q];
            cst[q] = sigm(fg) * cst[q] + sigm(ig) * tanh_f(gg);
            hq[q]  = sigm(og) * tanh_f(cst[q]);
        }
        __syncthreads();                            // all waves' A-reads complete
        #pragma unroll
        for (int q = 0; q < 4; ++q)
            xh[4 * lg + q][32 + w * 16 + r] = f2bf(hq[q]);
    }
    __syncthreads();                                // final h ready

    // hist_e = lrelu(h @ Wdyn^T + bdyn): 512 slots (16 m x 32 col), 2 per thread
    #pragma unroll
    for (int s2 = 0; s2 < 2; ++s2) {
        int s = tid + 256 * s2;
        int m = s >> 5, col = s & 31;
        float a = bdyn[col];
        for (int k = 0; k < ENC; ++k)
            a += bf2f(xh[m][32 + k]) * Wdyn[(size_t)col * ENC + k];
        enc_out[(size_t)(b0 + m) * (2 * DYN) + col] = lrelu(a);
    }
}

// ---------------- Kernel 2: neighbor scene (unchanged, f32 VALU) ----------------
__global__ __launch_bounds__(64) void nbr_scene_kernel(
    const float* __restrict__ hist, const float* __restrict__ nbrs,
    const int*   __restrict__ seg,
    const float* __restrict__ Wnbr, const float* __restrict__ bnbr,
    const float* __restrict__ Wdyn, const float* __restrict__ bdyn,
    float* __restrict__ enc_out)                    // [BHERO][64], cols 32..63
{
    const int b   = blockIdx.x;
    const int tid = threadIdx.x;

    __shared__ float rela_s[K_NBR][2 * T_IN + 1];
    __shared__ float scene_s[ENC];

    const int n0 = b * K_NBR;
    const int k  = tid >> 1, cch = tid & 1;
    const int hb = seg[n0 + k];
    for (int t = 0; t < T_IN; ++t) {
        float hv = hist[((size_t)t * BHERO + hb) * 2 + cch];
        float nv = nbrs[((size_t)t * N_NBR + n0 + k) * 2 + cch];
        rela_s[k][2*t + cch] = hv - nv;
    }
    __syncthreads();

    float wv[2 * T_IN];
    #pragma unroll
    for (int j = 0; j < 2 * T_IN; ++j) wv[j] = Wnbr[tid * (2*T_IN) + j];
    const float bn = bnbr[tid];

    float m = -1e30f;
    for (int kk = 0; kk < K_NBR; ++kk) {
        float a0 = 0.f, a1 = 0.f, a2 = 0.f, a3 = 0.f;
        #pragma unroll
        for (int j = 0; j < 2 * T_IN; j += 4) {
            a0 = fmaf(wv[j+0], rela_s[kk][j+0], a0);
            a1 = fmaf(wv[j+1], rela_s[kk][j+1], a1);
            a2 = fmaf(wv[j+2], rela_s[kk][j+2], a2);
            a3 = fmaf(wv[j+3], rela_s[kk][j+3], a3);
        }
        m = fmaxf(m, lrelu(bn + ((a0 + a1) + (a2 + a3))));
    }
    scene_s[tid] = m;
    __syncthreads();

    if (tid < DYN) {
        float a0 = 0.f, a1 = 0.f, a2 = 0.f, a3 = 0.f;
        #pragma unroll
        for (int j = 0; j < ENC; j += 4) {
            a0 = fmaf(Wdyn[tid*ENC + j + 0], scene_s[j + 0], a0);
            a1 = fmaf(Wdyn[tid*ENC + j + 1], scene_s[j + 1], a1);
            a2 = fmaf(Wdyn[tid*ENC + j + 2], scene_s[j + 2], a2);
            a3 = fmaf(Wdyn[tid*ENC + j + 3], scene_s[j + 3], a3);
        }
        enc_out[(size_t)b * (2*DYN) + DYN + tid] = lrelu(bdyn[tid] + ((a0 + a1) + (a2 + a3)));
    }
}

// ---------------- Kernel 3: decoder LSTM, MFMA version ----------------
// 512 threads (8 waves) per 16 heroes. Wave w owns units u0=w*16..u0+15 across the
// 4 gate blocks. K=128 in 4 chunks of 32; k = 32c + 8*lg + e on both A and B.
// B-frags (Whh_d) register-resident: 16 frags = 64 VGPRs. xW+bias precomputed as
// C-frag initializers. Output head fused via in-group shfl_xor reduction.
__global__ __launch_bounds__(512, 2) void decoder_mfma(
    const float* __restrict__ enc,                  // [BHERO][64]
    const float* __restrict__ Wih,  const float* __restrict__ Whh,
    const float* __restrict__ bih,  const float* __restrict__ bhh,
    const float* __restrict__ Wop,  const float* __restrict__ bop,
    float* __restrict__ fut)                        // [T_OUT][BHERO][2]
{
    const int b0  = blockIdx.x * 16;
    const int tid = threadIdx.x;
    const int w = tid >> 6, l = tid & 63, r = l & 15, lg = l >> 4;
    const int u0 = w * 16;

    __shared__ __align__(16) short hbuf[16][DROW];
    __shared__ __align__(16) float enc_s[16][2 * DYN];
    __shared__ float opart[8][16][2];

    for (int i = tid; i < 16 * DROW; i += 512) ((short*)hbuf)[i] = 0;
    for (int i = tid; i < 16 * 64;  i += 512)
        enc_s[i >> 6][i & 63] = enc[(size_t)(b0 + (i >> 6)) * 64 + (i & 63)];
    __syncthreads();

    // B-frags: 4 gate tiles x 4 k-chunks
    bf16x8 Bf[4][4];
    float  biasj[4];
    #pragma unroll
    for (int j = 0; j < 4; ++j) {
        const int col = j * DEC + u0 + r;
        biasj[j] = bih[col] + bhh[col];
        #pragma unroll
        for (int c = 0; c < 4; ++c) {
            const float* src = Whh + (size_t)col * DEC + c * 32 + 8 * lg;
            float4 f0 = *(const float4*)src;
            float4 f1 = *(const float4*)(src + 4);
            bf16x8 bb;
            bb[0]=f2bf(f0.x); bb[1]=f2bf(f0.y); bb[2]=f2bf(f0.z); bb[3]=f2bf(f0.w);
            bb[4]=f2bf(f1.x); bb[5]=f2bf(f1.y); bb[6]=f2bf(f1.z); bb[7]=f2bf(f1.w);
            Bf[j][c] = bb;
        }
    }

    // xw frags: xw[m][col] = enc[m] . Wih[col] + bias  (input constant over steps)
    f32x4 xwf[4];
    #pragma unroll
    for (int j = 0; j < 4; ++j) {
        const int col = j * DEC + u0 + r;
        float a0 = biasj[j], a1 = biasj[j], a2 = biasj[j], a3 = biasj[j];
        for (int k = 0; k < 2 * DYN; ++k) {
            float wv = Wih[(size_t)col * (2 * DYN) + k];
            a0 = fmaf(wv, enc_s[4*lg + 0][k], a0);
            a1 = fmaf(wv, enc_s[4*lg + 1][k], a1);
            a2 = fmaf(wv, enc_s[4*lg + 2][k], a2);
            a3 = fmaf(wv, enc_s[4*lg + 3][k], a3);
        }
        xwf[j] = (f32x4){a0, a1, a2, a3};
    }

    const float w0 = Wop[u0 + r];                   // Wop[0][unit]
    const float w1 = Wop[DEC + u0 + r];             // Wop[1][unit]
    f32x4 cst = {0.f, 0.f, 0.f, 0.f};

    for (int t = 0; t < T_OUT; ++t) {
        bf16x8 a_[4];
        #pragma unroll
        for (int c = 0; c < 4; ++c)
            a_[c] = *(const bf16x8*)&hbuf[r][(4 * c + lg) * 8];

        f32x4 acc[4];
        #pragma unroll
        for (int j = 0; j < 4; ++j) {
            acc[j] = xwf[j];
            #pragma unroll
            for (int c = 0; c < 4; ++c)
                acc[j] = __builtin_amdgcn_mfma_f32_16x16x32_bf16(a_[c], Bf[j][c], acc[j], 0, 0, 0);
        }

        float hq[4], p0[4], p1[4];
        #pragma unroll
        for (int q = 0; q < 4; ++q) {
            float ig = acc[0][q], fg = acc[1][q], gg = acc[2][q], og = acc[3][q];
            cst[q] = sigm(fg) * cst[q] + sigm(ig) * tanh_f(gg);
            hq[q]  = sigm(og) * tanh_f(cst[q]);
            p0[q]  = hq[q] * w0;
            p1[q]  = hq[q] * w1;
        }
        // reduce over r (16-lane group) for the output head
        #pragma unroll
        for (int msk = 1; msk < 16; msk <<= 1) {
            #pragma unroll
            for (int q = 0; q < 4; ++q) {
                p0[q] += __shfl_xor(p0[q], msk);
                p1[q] += __shfl_xor(p1[q], msk);
            }
        }
        __syncthreads();                            // all waves' A-reads complete
        #pragma unroll
        for (int q = 0; q < 4; ++q)
            hbuf[4 * lg + q][u0 + r] = f2bf(hq[q]);
        if (r == 0) {
            #pragma unroll
            for (int q = 0; q < 4; ++q) {
                opart[w][4 * lg + q][0] = p0[q];
                opart[w][4 * lg + q][1] = p1[q];
            }
        }
        __syncthreads();                            // h + opart ready
        if (tid < 16) {
            float o0 = bop[0], o1 = bop[1];
            #pragma unroll
            for (int ww = 0; ww < 8; ++ww) {
                o0 += opart[ww][tid][0];
                o1 += opart[ww][tid][1];
            }
            float2* dst = (float2*)(fut + ((size_t)t * BHERO + b0 + tid) * 2);
            *dst = make_float2(o0, o1);
        }
    }
}

extern "C" void kernel_launch(void* const* d_in, const int* in_sizes, int n_in,
                              void* d_out, int out_size, void* d_ws, size_t ws_size,
                              hipStream_t stream) {
    const float* hist  = (const float*)d_in[0];
    const float* nbrs  = (const float*)d_in[1];
    const float* Wip   = (const float*)d_in[2];
    const float* bip   = (const float*)d_in[3];
    const float* Wih_e = (const float*)d_in[4];
    const float* Whh_e = (const float*)d_in[5];
    const float* bih_e = (const float*)d_in[6];
    const float* bhh_e = (const float*)d_in[7];
    const float* Wdyn  = (const float*)d_in[8];
    const float* bdyn  = (const float*)d_in[9];
    const float* Wnbr  = (const float*)d_in[10];
    const float* bnbr  = (const float*)d_in[11];
    const float* Wih_d = (const float*)d_in[12];
    const float* Whh_d = (const float*)d_in[13];
    const float* bih_d = (const float*)d_in[14];
    const float* bhh_d = (const float*)d_in[15];
    const float* Wop   = (const float*)d_in[16];
    const float* bop   = (const float*)d_in[17];
    const int*   seg   = (const int*)d_in[18];

    float* fut    = (float*)d_out;
    float* enc_ws = (float*)d_ws;                   // [BHERO][64] = 1 MB scratch

    hipLaunchKernelGGL(ego_encoder_mfma, dim3(BHERO / 16), dim3(256), 0, stream,
                       hist, Wip, bip, Wih_e, Whh_e, bih_e, bhh_e, Wdyn, bdyn, enc_ws);
    hipLaunchKernelGGL(nbr_scene_kernel, dim3(BHERO), dim3(64), 0, stream,
                       hist, nbrs, seg, Wnbr, bnbr, Wdyn, bdyn, enc_ws);
    hipLaunchKernelGGL(decoder_mfma, dim3(BHERO / 16), dim3(512), 0, stream,
                       enc_ws, Wih_d, Whh_d, bih_d, bhh_d, Wop, bop, fut);
}

// Round 4
// 81.659 us; speedup vs baseline: 8.7691x; 1.5959x over previous
//
#include <hip/hip_runtime.h>
#include <hip/hip_bf16.h>

#define T_IN   16
#define T_OUT  25
#define BHERO  4096
#define K_NBR  32
#define N_NBR  (BHERO * K_NBR)
#define ENC    64
#define DEC    128
#define DYN    32
#define EMB    32

#define EROW   104        // encoder slab row: [emb 32 | h 64] = 96 bf16 + 8 pad (208B, 16B-aligned)
#define DROW   136        // decoder slab row: 128 bf16 + 8 pad (272B, 16B-aligned)

typedef __attribute__((ext_vector_type(8))) short bf16x8;   // 8 bf16 in 4 VGPRs
typedef __attribute__((ext_vector_type(4))) float f32x4;    // MFMA 16x16 C/D frag

__device__ __forceinline__ float lrelu(float x) { return x >= 0.f ? x : 0.1f * x; }
__device__ __forceinline__ float rcpf(float x)  { return __builtin_amdgcn_rcpf(x); }
// v_rcp_f32-based activations (~1 ulp) — avoids the ~10-instr IEEE div expansion
__device__ __forceinline__ float sigm(float x)  { return rcpf(1.f + __expf(-x)); }
__device__ __forceinline__ float tanh_f(float x) {
    float e = __expf(-2.f * fabsf(x));
    float t = (1.f - e) * rcpf(1.f + e);
    return x >= 0.f ? t : -t;
}
__device__ __forceinline__ short f2bf(float x) {            // f32 -> bf16, round-nearest-even
    unsigned u = __float_as_uint(x);
    return (short)((u + 0x7FFFu + ((u >> 16) & 1u)) >> 16);
}
__device__ __forceinline__ float bf2f(short s) {
    return __uint_as_float(((unsigned)(unsigned short)s) << 16);
}

// ---------------- Kernel 1: ego encoder, MFMA + slab-ring version ----------------
// 256 threads (4 waves) per 16 heroes. Wave w owns units w*16..w*16+15 across the 4
// gate blocks. K=96=[emb 32|h 64] in 3 chunks of 32; k = 32c + 8*lg + e on A and B.
// ONE barrier per step: step t reads slab[t], writes h(t) into slab[t+1] (disjoint).
// emb(t) for all t precomputed into the slabs before the loop.
__global__ __launch_bounds__(256, 2) void ego_encoder_mfma(
    const float* __restrict__ hist,
    const float* __restrict__ Wip,  const float* __restrict__ bip,
    const float* __restrict__ Wih,  const float* __restrict__ Whh,
    const float* __restrict__ bih,  const float* __restrict__ bhh,
    const float* __restrict__ Wdyn, const float* __restrict__ bdyn,
    float* __restrict__ enc_out)                 // [BHERO][64], cols 0..31
{
    const int b0  = blockIdx.x * 16;
    const int tid = threadIdx.x;
    const int w = tid >> 6, l = tid & 63, r = l & 15, lg = l >> 4;

    __shared__ __align__(16) short slab[T_IN + 1][16][EROW];   // 56.6 KB
    __shared__ float wip_s[EMB][2];
    __shared__ float bip_s[EMB];

    if (tid < EMB) {
        wip_s[tid][0] = Wip[2 * tid];
        wip_s[tid][1] = Wip[2 * tid + 1];
        bip_s[tid]    = bip[tid];
    }
    // zero h region of slab[0]
    for (int i = tid; i < 16 * 64; i += 256) slab[0][i >> 6][32 + (i & 63)] = 0;

    // B-frags in registers: 4 gate tiles x 3 k-chunks (c0 = Wih/emb, c1,c2 = Whh)
    bf16x8 Bf[4][3];
    float  biasj[4];
    #pragma unroll
    for (int j = 0; j < 4; ++j) {
        const int col = j * ENC + w * 16 + r;
        biasj[j] = bih[col] + bhh[col];
        #pragma unroll
        for (int c = 0; c < 3; ++c) {
            const float* src = (c == 0) ? (Wih + (size_t)col * EMB + 8 * lg)
                                        : (Whh + (size_t)col * ENC + (c - 1) * 32 + 8 * lg);
            float4 f0 = *(const float4*)src;
            float4 f1 = *(const float4*)(src + 4);
            bf16x8 bb;
            bb[0]=f2bf(f0.x); bb[1]=f2bf(f0.y); bb[2]=f2bf(f0.z); bb[3]=f2bf(f0.w);
            bb[4]=f2bf(f1.x); bb[5]=f2bf(f1.y); bb[6]=f2bf(f1.z); bb[7]=f2bf(f1.w);
            Bf[j][c] = bb;
        }
    }
    __syncthreads();                              // wip_s ready

    // emb prefill: thread (t=tid>>4, m=tid&15) computes emb[t][m][0..31]
    {
        const int t = tid >> 4, m = tid & 15;
        float2 hv = *(const float2*)&hist[((size_t)t * BHERO + b0 + m) * 2];
        #pragma unroll
        for (int jb = 0; jb < 4; ++jb) {
            bf16x8 v;
            #pragma unroll
            for (int e = 0; e < 8; ++e) {
                int j = jb * 8 + e;
                v[e] = f2bf(lrelu(hv.x * wip_s[j][0] + hv.y * wip_s[j][1] + bip_s[j]));
            }
            *(bf16x8*)&slab[t][m][jb * 8] = v;
        }
    }
    f32x4 cst = {0.f, 0.f, 0.f, 0.f};             // cell state: hero 4*lg+q, unit w*16+r
    __syncthreads();                              // emb + h(0) ready

    for (int t = 0; t < T_IN; ++t) {
        const short* rowp = &slab[t][r][0];
        bf16x8 a0 = *(const bf16x8*)(rowp + (0 + lg) * 8);
        bf16x8 a1 = *(const bf16x8*)(rowp + (4 + lg) * 8);
        bf16x8 a2 = *(const bf16x8*)(rowp + (8 + lg) * 8);

        f32x4 acc[4];
        #pragma unroll
        for (int j = 0; j < 4; ++j) {
            acc[j] = (f32x4){biasj[j], biasj[j], biasj[j], biasj[j]};
            acc[j] = __builtin_amdgcn_mfma_f32_16x16x32_bf16(a0, Bf[j][0], acc[j], 0, 0, 0);
            acc[j] = __builtin_amdgcn_mfma_f32_16x16x32_bf16(a1, Bf[j][1], acc[j], 0, 0, 0);
            acc[j] = __builtin_amdgcn_mfma_f32_16x16x32_bf16(a2, Bf[j][2], acc[j], 0, 0, 0);
        }
        #pragma unroll
        for (int q = 0; q < 4; ++q) {
            float ig = acc[0][q], fg = acc[1][q], gg = acc[2][q], og = acc[3][q];
            cst[q] = sigm(fg) * cst[q] + sigm(ig) * tanh_f(gg);
            slab[t + 1][4 * lg + q][32 + w * 16 + r] = f2bf(sigm(og) * tanh_f(cst[q]));
        }
        __syncthreads();                          // h(t) ready (no WAR: slab[t+1] wasn't read)
    }

    // hist_e = lrelu(h @ Wdyn^T + bdyn) from slab[T_IN]
    #pragma unroll
    for (int s2 = 0; s2 < 2; ++s2) {
        int s = tid + 256 * s2;
        int m = s >> 5, col = s & 31;
        float a = bdyn[col];
        #pragma unroll 8
        for (int k = 0; k < ENC; ++k)
            a += bf2f(slab[T_IN][m][32 + k]) * Wdyn[(size_t)col * ENC + k];
        enc_out[(size_t)(b0 + m) * (2 * DYN) + col] = lrelu(a);
    }
}

// ---------------- Kernel 2: neighbor scene (f32 VALU) ----------------
__global__ __launch_bounds__(64) void nbr_scene_kernel(
    const float* __restrict__ hist, const float* __restrict__ nbrs,
    const int*   __restrict__ seg,
    const float* __restrict__ Wnbr, const float* __restrict__ bnbr,
    const float* __restrict__ Wdyn, const float* __restrict__ bdyn,
    float* __restrict__ enc_out)                    // [BHERO][64], cols 32..63
{
    const int b   = blockIdx.x;
    const int tid = threadIdx.x;

    __shared__ float rela_s[K_NBR][2 * T_IN + 1];
    __shared__ float scene_s[ENC];

    const int n0 = b * K_NBR;
    const int k  = tid >> 1, cch = tid & 1;
    const int hb = seg[n0 + k];
    for (int t = 0; t < T_IN; ++t) {
        float hv = hist[((size_t)t * BHERO + hb) * 2 + cch];
        float nv = nbrs[((size_t)t * N_NBR + n0 + k) * 2 + cch];
        rela_s[k][2*t + cch] = hv - nv;
    }
    __syncthreads();

    float wv[2 * T_IN];
    #pragma unroll
    for (int j = 0; j < 2 * T_IN; ++j) wv[j] = Wnbr[tid * (2*T_IN) + j];
    const float bn = bnbr[tid];

    float m = -1e30f;
    for (int kk = 0; kk < K_NBR; ++kk) {
        float a0 = 0.f, a1 = 0.f, a2 = 0.f, a3 = 0.f;
        #pragma unroll
        for (int j = 0; j < 2 * T_IN; j += 4) {
            a0 = fmaf(wv[j+0], rela_s[kk][j+0], a0);
            a1 = fmaf(wv[j+1], rela_s[kk][j+1], a1);
            a2 = fmaf(wv[j+2], rela_s[kk][j+2], a2);
            a3 = fmaf(wv[j+3], rela_s[kk][j+3], a3);
        }
        m = fmaxf(m, lrelu(bn + ((a0 + a1) + (a2 + a3))));
    }
    scene_s[tid] = m;
    __syncthreads();

    if (tid < DYN) {
        float a0 = 0.f, a1 = 0.f, a2 = 0.f, a3 = 0.f;
        #pragma unroll
        for (int j = 0; j < ENC; j += 4) {
            a0 = fmaf(Wdyn[tid*ENC + j + 0], scene_s[j + 0], a0);
            a1 = fmaf(Wdyn[tid*ENC + j + 1], scene_s[j + 1], a1);
            a2 = fmaf(Wdyn[tid*ENC + j + 2], scene_s[j + 2], a2);
            a3 = fmaf(Wdyn[tid*ENC + j + 3], scene_s[j + 3], a3);
        }
        enc_out[(size_t)b * (2*DYN) + DYN + tid] = lrelu(bdyn[tid] + ((a0 + a1) + (a2 + a3)));
    }
}

// ---------------- Kernel 3: decoder LSTM, MFMA + h-history slab version ----------------
// 512 threads (8 waves) per 16 heroes. Wave w owns units u0=w*16..u0+15 across the
// 4 gate blocks. K=128 in 4 chunks; k = 32c + 8*lg + e on A and B. B-frags (Whh_d)
// register-resident. xw precomputed via MFMA (enc x Wih). ONE barrier per step:
// step t reads hist_s[t], writes h(t) into hist_s[t+1]. Output head deferred:
// fut = hist_s[1..25] @ Wop^T + bop computed after the loop (400 threads, 1 each).
__global__ __launch_bounds__(512, 2) void decoder_mfma(
    const float* __restrict__ enc,                  // [BHERO][64]
    const float* __restrict__ Wih,  const float* __restrict__ Whh,
    const float* __restrict__ bih,  const float* __restrict__ bhh,
    const float* __restrict__ Wop,  const float* __restrict__ bop,
    float* __restrict__ fut)                        // [T_OUT][BHERO][2]
{
    const int b0  = blockIdx.x * 16;
    const int tid = threadIdx.x;
    const int w = tid >> 6, l = tid & 63, r = l & 15, lg = l >> 4;
    const int u0 = w * 16;

    __shared__ __align__(16) short hist_s[T_OUT + 1][16][DROW];   // 113.2 KB
    __shared__ __align__(16) float enc_s[16][68];                 // +4 pad: 2-way banks max
    __shared__ float wop_s[2][DEC];
    __shared__ float bop_s[2];

    for (int i = tid; i < 16 * 64; i += 512)
        enc_s[i >> 6][i & 63] = enc[(size_t)(b0 + (i >> 6)) * 64 + (i & 63)];
    if (tid < 2 * DEC) wop_s[tid >> 7][tid & 127] = Wop[tid];
    if (tid < 2)       bop_s[tid] = bop[tid];
    for (int i = tid; i < 16 * DROW; i += 512) ((short*)hist_s)[i] = 0;   // zero slab 0

    // B-frags: 4 gate tiles x 4 k-chunks (64 VGPRs)
    bf16x8 Bf[4][4];
    float  biasj[4];
    #pragma unroll
    for (int j = 0; j < 4; ++j) {
        const int col = j * DEC + u0 + r;
        biasj[j] = bih[col] + bhh[col];
        #pragma unroll
        for (int c = 0; c < 4; ++c) {
            const float* src = Whh + (size_t)col * DEC + c * 32 + 8 * lg;
            float4 f0 = *(const float4*)src;
            float4 f1 = *(const float4*)(src + 4);
            bf16x8 bb;
            bb[0]=f2bf(f0.x); bb[1]=f2bf(f0.y); bb[2]=f2bf(f0.z); bb[3]=f2bf(f0.w);
            bb[4]=f2bf(f1.x); bb[5]=f2bf(f1.y); bb[6]=f2bf(f1.z); bb[7]=f2bf(f1.w);
            Bf[j][c] = bb;
        }
    }
    __syncthreads();                                // enc_s ready

    // xw frags via MFMA: A = enc rows (bf16), B = Wih frags. K=64 in 2 chunks.
    f32x4 xwf[4];
    {
        bf16x8 aE[2];
        #pragma unroll
        for (int c = 0; c < 2; ++c) {
            float4 f0 = *(const float4*)&enc_s[r][c * 32 + 8 * lg];
            float4 f1 = *(const float4*)&enc_s[r][c * 32 + 8 * lg + 4];
            bf16x8 v;
            v[0]=f2bf(f0.x); v[1]=f2bf(f0.y); v[2]=f2bf(f0.z); v[3]=f2bf(f0.w);
            v[4]=f2bf(f1.x); v[5]=f2bf(f1.y); v[6]=f2bf(f1.z); v[7]=f2bf(f1.w);
            aE[c] = v;
        }
        #pragma unroll
        for (int j = 0; j < 4; ++j) {
            const int col = j * DEC + u0 + r;
            f32x4 a = {biasj[j], biasj[j], biasj[j], biasj[j]};
            #pragma unroll
            for (int c = 0; c < 2; ++c) {
                const float* src = Wih + (size_t)col * (2 * DYN) + c * 32 + 8 * lg;
                float4 f0 = *(const float4*)src;
                float4 f1 = *(const float4*)(src + 4);
                bf16x8 bb;
                bb[0]=f2bf(f0.x); bb[1]=f2bf(f0.y); bb[2]=f2bf(f0.z); bb[3]=f2bf(f0.w);
                bb[4]=f2bf(f1.x); bb[5]=f2bf(f1.y); bb[6]=f2bf(f1.z); bb[7]=f2bf(f1.w);
                a = __builtin_amdgcn_mfma_f32_16x16x32_bf16(aE[c], bb, a, 0, 0, 0);
            }
            xwf[j] = a;
        }
    }

    f32x4 cst = {0.f, 0.f, 0.f, 0.f};
    __syncthreads();                                // slab 0 zeros ready

    for (int t = 0; t < T_OUT; ++t) {
        const short* rowp = &hist_s[t][r][0];
        bf16x8 a_[4];
        #pragma unroll
        for (int c = 0; c < 4; ++c)
            a_[c] = *(const bf16x8*)(rowp + (4 * c + lg) * 8);

        f32x4 acc[4];
        #pragma unroll
        for (int j = 0; j < 4; ++j) {
            acc[j] = xwf[j];
            #pragma unroll
            for (int c = 0; c < 4; ++c)
                acc[j] = __builtin_amdgcn_mfma_f32_16x16x32_bf16(a_[c], Bf[j][c], acc[j], 0, 0, 0);
        }
        #pragma unroll
        for (int q = 0; q < 4; ++q) {
            float ig = acc[0][q], fg = acc[1][q], gg = acc[2][q], og = acc[3][q];
            cst[q] = sigm(fg) * cst[q] + sigm(ig) * tanh_f(gg);
            hist_s[t + 1][4 * lg + q][u0 + r] = f2bf(sigm(og) * tanh_f(cst[q]));
        }
        __syncthreads();                            // h(t) ready (no WAR: slab t+1 unread)
    }

    // Deferred output head: 400 (t,m) pairs, one per thread.
    if (tid < T_OUT * 16) {
        const int t = tid >> 4, m = tid & 15;
        const short* hp = &hist_s[t + 1][m][0];
        float o0 = bop_s[0], o1 = bop_s[1];
        #pragma unroll
        for (int ub = 0; ub < DEC / 8; ++ub) {
            bf16x8 hv = *(const bf16x8*)(hp + ub * 8);
            #pragma unroll
            for (int e = 0; e < 8; ++e) {
                float h = bf2f(hv[e]);
                o0 = fmaf(h, wop_s[0][ub * 8 + e], o0);
                o1 = fmaf(h, wop_s[1][ub * 8 + e], o1);
            }
        }
        *(float2*)(fut + ((size_t)t * BHERO + b0 + m) * 2) = make_float2(o0, o1);
    }
}

extern "C" void kernel_launch(void* const* d_in, const int* in_sizes, int n_in,
                              void* d_out, int out_size, void* d_ws, size_t ws_size,
                              hipStream_t stream) {
    const float* hist  = (const float*)d_in[0];
    const float* nbrs  = (const float*)d_in[1];
    const float* Wip   = (const float*)d_in[2];
    const float* bip   = (const float*)d_in[3];
    const float* Wih_e = (const float*)d_in[4];
    const float* Whh_e = (const float*)d_in[5];
    const float* bih_e = (const float*)d_in[6];
    const float* bhh_e = (const float*)d_in[7];
    const float* Wdyn  = (const float*)d_in[8];
    const float* bdyn  = (const float*)d_in[9];
    const float* Wnbr  = (const float*)d_in[10];
    const float* bnbr  = (const float*)d_in[11];
    const float* Wih_d = (const float*)d_in[12];
    const float* Whh_d = (const float*)d_in[13];
    const float* bih_d = (const float*)d_in[14];
    const float* bhh_d = (const float*)d_in[15];
    const float* Wop   = (const float*)d_in[16];
    const float* bop   = (const float*)d_in[17];
    const int*   seg   = (const int*)d_in[18];

    float* fut    = (float*)d_out;
    float* enc_ws = (float*)d_ws;                   // [BHERO][64] = 1 MB scratch

    hipLaunchKernelGGL(ego_encoder_mfma, dim3(BHERO / 16), dim3(256), 0, stream,
                       hist, Wip, bip, Wih_e, Whh_e, bih_e, bhh_e, Wdyn, bdyn, enc_ws);
    hipLaunchKernelGGL(nbr_scene_kernel, dim3(BHERO), dim3(64), 0, stream,
                       hist, nbrs, seg, Wnbr, bnbr, Wdyn, bdyn, enc_ws);
    hipLaunchKernelGGL(decoder_mfma, dim3(BHERO / 16), dim3(512), 0, stream,
                       enc_ws, Wih_d, Whh_d, bih_d, bhh_d, Wop, bop, fut);
}

// Round 5
// 64.223 us; speedup vs baseline: 11.1500x; 1.2715x over previous
//
#include <hip/hip_runtime.h>
#include <hip/hip_bf16.h>

#define T_IN   16
#define T_OUT  25
#define BHERO  4096
#define K_NBR  32
#define N_NBR  (BHERO * K_NBR)
#define ENC    64
#define DEC    128
#define DYN    32
#define EMB    32

#define EROW   104        // encoder slab row: [emb 32 | h 64] + pad -> 208 B (16B-mult)
#define DROW   136        // decoder slab row: 128 bf16 + pad -> 272 B (16B-mult)
#define RROW   40         // rela row: 32 feat + 8 pad -> 80 B (16B-mult)

// ---- LDS layout (byte offsets into one raw pool; phases overlay) ----
// Phase E (prologue+encoder):  slab[17][16][EROW] @0 (56576) | rela[512][RROW] @56576 (40960) | pmax[32][64] f32 @97536 (8192)
// Phase D (decoder):           hist_s[26][16][DROW] @0 (113152)   (overlays slab/rela/pmax after they are dead)
// Persistent small:            enc_s[16][68] f32 @113152 | wop[2][128] @117504 | wip[32][2] @118528 | bip[32] @118784 | bop[2] @118912
#define OFF_RELA   56576
#define OFF_PMAX   97536
#define OFF_ENC    113152
#define OFF_WOP    117504
#define OFF_WIP    118528
#define OFF_BIP    118784
#define OFF_BOP    118912
#define LDS_TOTAL  118928

typedef __attribute__((ext_vector_type(8))) short bf16x8;   // 8 bf16 in 4 VGPRs
typedef __attribute__((ext_vector_type(4))) float f32x4;    // MFMA 16x16 C/D frag

__device__ __forceinline__ float lrelu(float x) { return x >= 0.f ? x : 0.1f * x; }
__device__ __forceinline__ float rcpf(float x)  { return __builtin_amdgcn_rcpf(x); }
// sigm: mul,exp,add,rcp (4 ops). tanh(x) = 2*sigm(2x)-1, branch-free (6 ops);
// saturates correctly at +-inf via v_exp/v_rcp semantics.
__device__ __forceinline__ float sigm(float x)  { return rcpf(1.f + __expf(-x)); }
__device__ __forceinline__ float tanhv(float x) {
    return fmaf(2.f, rcpf(1.f + __expf(-2.f * x)), -1.f);
}
__device__ __forceinline__ short f2bf(float x) {            // f32 -> bf16 RNE
    unsigned u = __float_as_uint(x);
    return (short)((u + 0x7FFFu + ((u >> 16) & 1u)) >> 16);
}
__device__ __forceinline__ float bf2f(short s) {
    return __uint_as_float(((unsigned)(unsigned short)s) << 16);
}

// ================= fused highwayNet forward: 256 WGs x 512 threads, 16 heroes/WG =================
__global__ __launch_bounds__(512, 2) void highway_fused(
    const float* __restrict__ hist,  const float* __restrict__ nbrs,
    const float* __restrict__ Wip,   const float* __restrict__ bip,
    const float* __restrict__ WihE,  const float* __restrict__ WhhE,
    const float* __restrict__ bihE,  const float* __restrict__ bhhE,
    const float* __restrict__ Wdyn,  const float* __restrict__ bdyn,
    const float* __restrict__ Wnbr,  const float* __restrict__ bnbr,
    const float* __restrict__ WihD,  const float* __restrict__ WhhD,
    const float* __restrict__ bihD,  const float* __restrict__ bhhD,
    const float* __restrict__ Wop,   const float* __restrict__ bop,
    const int*   __restrict__ seg,
    float* __restrict__ fut)                        // [T_OUT][BHERO][2]
{
    __shared__ __align__(16) char lds_raw[LDS_TOTAL];
    auto slab   = (short (*)[16][EROW])  lds_raw;                   // [17][16][EROW]
    auto rela   = (short (*)[RROW])     (lds_raw + OFF_RELA);       // [512][RROW]
    auto pmax   = (float (*)[ENC])      (lds_raw + OFF_PMAX);       // [32][64]
    auto hist_s = (short (*)[16][DROW])  lds_raw;                   // [26][16][DROW]
    auto enc_s  = (float (*)[68])       (lds_raw + OFF_ENC);        // [16][68]
    auto wop_s  = (float (*)[DEC])      (lds_raw + OFF_WOP);        // [2][128]
    auto wip_s  = (float (*)[2])        (lds_raw + OFF_WIP);        // [32][2]
    auto bip_s  = (float*)              (lds_raw + OFF_BIP);        // [32]
    auto bop_s  = (float*)              (lds_raw + OFF_BOP);        // [2]

    const int b0  = blockIdx.x * 16;
    const int n0  = blockIdx.x * 512;               // first neighbor row of this WG
    const int tid = threadIdx.x;
    const int w = tid >> 6, l = tid & 63, r = l & 15, lg = l >> 4;

    // ---------------- P0: small stages + rela staging ----------------
    if (tid < EMB) {
        wip_s[tid][0] = Wip[2 * tid];
        wip_s[tid][1] = Wip[2 * tid + 1];
        bip_s[tid]    = bip[tid];
    }
    if (tid < 2 * DEC) wop_s[tid >> 7][tid & 127] = Wop[tid];
    if (tid < 2)       bop_s[tid] = bop[tid];
    for (int i = tid; i < 16 * ENC; i += 512) slab[0][i >> 6][32 + (i & 63)] = 0;

    // nbr B-frags: col-tile ct, lane holds Wnbr[col=ct*16+r][k=8*lg+e]
    bf16x8 BfN[4];
    float  biasn[4];
    #pragma unroll
    for (int ct = 0; ct < 4; ++ct) {
        const int col = ct * 16 + r;
        biasn[ct] = bnbr[col];
        const float* src = Wnbr + (size_t)col * (2 * T_IN) + 8 * lg;
        float4 f0 = *(const float4*)src;
        float4 f1 = *(const float4*)(src + 4);
        bf16x8 bb;
        bb[0]=f2bf(f0.x); bb[1]=f2bf(f0.y); bb[2]=f2bf(f0.z); bb[3]=f2bf(f0.w);
        bb[4]=f2bf(f1.x); bb[5]=f2bf(f1.y); bb[6]=f2bf(f1.z); bb[7]=f2bf(f1.w);
        BfN[ct] = bb;
    }

    // encoder B-frags (waves 0-3 only): gate tile j, k-chunk c (c0 = Wih over emb)
    bf16x8 BfE[4][3];
    float  biasjE[4];
    if (tid < 256) {
        #pragma unroll
        for (int j = 0; j < 4; ++j) {
            const int col = j * ENC + w * 16 + r;
            biasjE[j] = bihE[col] + bhhE[col];
            #pragma unroll
            for (int c = 0; c < 3; ++c) {
                const float* src = (c == 0) ? (WihE + (size_t)col * EMB + 8 * lg)
                                            : (WhhE + (size_t)col * ENC + (c - 1) * 32 + 8 * lg);
                float4 f0 = *(const float4*)src;
                float4 f1 = *(const float4*)(src + 4);
                bf16x8 bb;
                bb[0]=f2bf(f0.x); bb[1]=f2bf(f0.y); bb[2]=f2bf(f0.z); bb[3]=f2bf(f0.w);
                bb[4]=f2bf(f1.x); bb[5]=f2bf(f1.y); bb[6]=f2bf(f1.z); bb[7]=f2bf(f1.w);
                BfE[j][c] = bb;
            }
        }
    }

    // rela staging: thread owns neighbor row n = tid; rela[n][2t+ch] = hist[t][seg[n]][ch] - nbrs[t][n][ch]
    {
        const int n  = tid;
        const int hb = seg[n0 + n];                 // faithful segment gather
        unsigned* dst = (unsigned*)&rela[n][0];
        for (int t = 0; t < T_IN; ++t) {
            float2 hv = *(const float2*)&hist[((size_t)t * BHERO + hb) * 2];
            float2 nv = *(const float2*)&nbrs[((size_t)t * N_NBR + n0 + n) * 2];
            unsigned p = (unsigned)(unsigned short)f2bf(hv.x - nv.x)
                       | ((unsigned)(unsigned short)f2bf(hv.y - nv.y) << 16);
            dst[t] = p;
        }
    }
    __syncthreads();                                // wip/rela/slab0 ready

    // ---------------- P1: emb staging + nbr GEMM + segment max ----------------
    if (tid < 256) {                                // emb for (t, m)
        const int t = tid >> 4, m = tid & 15;
        float2 hv = *(const float2*)&hist[((size_t)t * BHERO + b0 + m) * 2];
        #pragma unroll
        for (int jb = 0; jb < 4; ++jb) {
            bf16x8 v;
            #pragma unroll
            for (int e = 0; e < 8; ++e) {
                int j = jb * 8 + e;
                v[e] = f2bf(lrelu(hv.x * wip_s[j][0] + hv.y * wip_s[j][1] + bip_s[j]));
            }
            *(bf16x8*)&slab[t][m][jb * 8] = v;
        }
    }
    // nbr GEMM: 32 row-tiles x 4 col-tiles, K=32 single chunk; wave w owns rt in {w, w+8, w+16, w+24}
    #pragma unroll
    for (int rr = 0; rr < 4; ++rr) {
        const int rt = w + 8 * rr;
        bf16x8 a = *(const bf16x8*)&rela[rt * 16 + r][8 * lg];
        #pragma unroll
        for (int ct = 0; ct < 4; ++ct) {
            f32x4 acc = {biasn[ct], biasn[ct], biasn[ct], biasn[ct]};
            acc = __builtin_amdgcn_mfma_f32_16x16x32_bf16(a, BfN[ct], acc, 0, 0, 0);
            // raw max over the 16 rows of this row-tile (lrelu deferred: monotone)
            float m4 = fmaxf(fmaxf(acc[0], acc[1]), fmaxf(acc[2], acc[3]));
            m4 = fmaxf(m4, __shfl_xor(m4, 16));
            m4 = fmaxf(m4, __shfl_xor(m4, 32));
            if (l < 16) pmax[rt][ct * 16 + r] = m4;
        }
    }
    f32x4 cstE = {0.f, 0.f, 0.f, 0.f};
    __syncthreads();                                // emb + pmax ready

    // ---------------- P2: encoder LSTM, 16 steps (waves 0-3) ----------------
    for (int t = 0; t < T_IN; ++t) {
        if (tid < 256) {
            const short* rowp = &slab[t][r][0];
            bf16x8 a0 = *(const bf16x8*)(rowp + (0 + lg) * 8);
            bf16x8 a1 = *(const bf16x8*)(rowp + (4 + lg) * 8);
            bf16x8 a2 = *(const bf16x8*)(rowp + (8 + lg) * 8);
            f32x4 acc[4];
            #pragma unroll
            for (int j = 0; j < 4; ++j) {
                acc[j] = (f32x4){biasjE[j], biasjE[j], biasjE[j], biasjE[j]};
                acc[j] = __builtin_amdgcn_mfma_f32_16x16x32_bf16(a0, BfE[j][0], acc[j], 0, 0, 0);
                acc[j] = __builtin_amdgcn_mfma_f32_16x16x32_bf16(a1, BfE[j][1], acc[j], 0, 0, 0);
                acc[j] = __builtin_amdgcn_mfma_f32_16x16x32_bf16(a2, BfE[j][2], acc[j], 0, 0, 0);
            }
            #pragma unroll
            for (int q = 0; q < 4; ++q) {
                float i = sigm(acc[0][q]);
                float f = sigm(acc[1][q]);
                float g = tanhv(acc[2][q]);
                float o = sigm(acc[3][q]);
                float cc = fmaf(f, cstE[q], i * g);
                cstE[q] = cc;
                slab[t + 1][4 * lg + q][32 + w * 16 + r] = f2bf(o * tanhv(cc));
            }
        }
        __syncthreads();                            // h(t) ready (slab[t+1] was unread)
    }

    // ---------------- P3: build enc_s = [hist_e | scene_d], zero decoder slab 0 ----------------
    #pragma unroll
    for (int it = 0; it < 2; ++it) {
        const int s = tid + 512 * it;               // 1024 tasks: (m, col)
        const int m = s >> 6, col = s & 63;
        const float* wd = Wdyn + (size_t)(col & 31) * ENC;
        float a = bdyn[col & 31];
        if (col < 32) {
            const short* hp = &slab[T_IN][m][32];
            #pragma unroll 8
            for (int k = 0; k < ENC; ++k) a = fmaf(bf2f(hp[k]), wd[k], a);
        } else {
            #pragma unroll 8
            for (int k = 0; k < ENC; ++k) {
                float sv = lrelu(fmaxf(pmax[2 * m][k], pmax[2 * m + 1][k]));
                a = fmaf(sv, wd[k], a);
            }
        }
        enc_s[m][col] = lrelu(a);
    }
    for (int i = tid; i < 16 * DROW; i += 512) ((short*)hist_s)[i] = 0;   // zero h(0)
    __syncthreads();                                // enc_s + decoder slab0 ready

    // ---------------- P4: decoder LSTM, 25 steps (all 8 waves) ----------------
    const int u0 = w * 16;
    bf16x8 BfD[4][4];
    float  biasjD[4];
    #pragma unroll
    for (int j = 0; j < 4; ++j) {
        const int col = j * DEC + u0 + r;
        biasjD[j] = bihD[col] + bhhD[col];
        #pragma unroll
        for (int c = 0; c < 4; ++c) {
            const float* src = WhhD + (size_t)col * DEC + c * 32 + 8 * lg;
            float4 f0 = *(const float4*)src;
            float4 f1 = *(const float4*)(src + 4);
            bf16x8 bb;
            bb[0]=f2bf(f0.x); bb[1]=f2bf(f0.y); bb[2]=f2bf(f0.z); bb[3]=f2bf(f0.w);
            bb[4]=f2bf(f1.x); bb[5]=f2bf(f1.y); bb[6]=f2bf(f1.z); bb[7]=f2bf(f1.w);
            BfD[j][c] = bb;
        }
    }
    // xw frags via MFMA: A = enc rows (bf16 from enc_s), B = Wih frags; K=64 in 2 chunks
    f32x4 xwf[4];
    {
        bf16x8 aE[2];
        #pragma unroll
        for (int c = 0; c < 2; ++c) {
            float4 f0 = *(const float4*)&enc_s[r][c * 32 + 8 * lg];
            float4 f1 = *(const float4*)&enc_s[r][c * 32 + 8 * lg + 4];
            bf16x8 v;
            v[0]=f2bf(f0.x); v[1]=f2bf(f0.y); v[2]=f2bf(f0.z); v[3]=f2bf(f0.w);
            v[4]=f2bf(f1.x); v[5]=f2bf(f1.y); v[6]=f2bf(f1.z); v[7]=f2bf(f1.w);
            aE[c] = v;
        }
        #pragma unroll
        for (int j = 0; j < 4; ++j) {
            const int col = j * DEC + u0 + r;
            f32x4 a = {biasjD[j], biasjD[j], biasjD[j], biasjD[j]};
            #pragma unroll
            for (int c = 0; c < 2; ++c) {
                const float* src = WihD + (size_t)col * (2 * DYN) + c * 32 + 8 * lg;
                float4 f0 = *(const float4*)src;
                float4 f1 = *(const float4*)(src + 4);
                bf16x8 bb;
                bb[0]=f2bf(f0.x); bb[1]=f2bf(f0.y); bb[2]=f2bf(f0.z); bb[3]=f2bf(f0.w);
                bb[4]=f2bf(f1.x); bb[5]=f2bf(f1.y); bb[6]=f2bf(f1.z); bb[7]=f2bf(f1.w);
                a = __builtin_amdgcn_mfma_f32_16x16x32_bf16(aE[c], bb, a, 0, 0, 0);
            }
            xwf[j] = a;
        }
    }

    f32x4 cst = {0.f, 0.f, 0.f, 0.f};
    for (int t = 0; t < T_OUT; ++t) {
        const short* rowp = &hist_s[t][r][0];
        bf16x8 a_[4];
        #pragma unroll
        for (int c = 0; c < 4; ++c)
            a_[c] = *(const bf16x8*)(rowp + (4 * c + lg) * 8);
        f32x4 acc[4];
        #pragma unroll
        for (int j = 0; j < 4; ++j) {
            acc[j] = xwf[j];
            #pragma unroll
            for (int c = 0; c < 4; ++c)
                acc[j] = __builtin_amdgcn_mfma_f32_16x16x32_bf16(a_[c], BfD[j][c], acc[j], 0, 0, 0);
        }
        #pragma unroll
        for (int q = 0; q < 4; ++q) {
            float i = sigm(acc[0][q]);
            float f = sigm(acc[1][q]);
            float g = tanhv(acc[2][q]);
            float o = sigm(acc[3][q]);
            float cc = fmaf(f, cst[q], i * g);
            cst[q] = cc;
            hist_s[t + 1][4 * lg + q][u0 + r] = f2bf(o * tanhv(cc));
        }
        __syncthreads();                            // h(t) ready (slab t+1 was unread)
    }

    // ---------------- P5: deferred output head ----------------
    if (tid < T_OUT * 16) {
        const int t = tid >> 4, m = tid & 15;
        const short* hp = &hist_s[t + 1][m][0];
        float o0 = bop_s[0], o1 = bop_s[1];
        #pragma unroll
        for (int ub = 0; ub < DEC / 8; ++ub) {
            bf16x8 hv = *(const bf16x8*)(hp + ub * 8);
            #pragma unroll
            for (int e = 0; e < 8; ++e) {
                float h = bf2f(hv[e]);
                o0 = fmaf(h, wop_s[0][ub * 8 + e], o0);
                o1 = fmaf(h, wop_s[1][ub * 8 + e], o1);
            }
        }
        *(float2*)(fut + ((size_t)t * BHERO + b0 + m) * 2) = make_float2(o0, o1);
    }
}

extern "C" void kernel_launch(void* const* d_in, const int* in_sizes, int n_in,
                              void* d_out, int out_size, void* d_ws, size_t ws_size,
                              hipStream_t stream) {
    (void)d_ws; (void)ws_size; (void)in_sizes; (void)n_in; (void)out_size;
    const float* hist  = (const float*)d_in[0];
    const float* nbrs  = (const float*)d_in[1];
    const float* Wip   = (const float*)d_in[2];
    const float* bip   = (const float*)d_in[3];
    const float* Wih_e = (const float*)d_in[4];
    const float* Whh_e = (const float*)d_in[5];
    const float* bih_e = (const float*)d_in[6];
    const float* bhh_e = (const float*)d_in[7];
    const float* Wdyn  = (const float*)d_in[8];
    const float* bdyn  = (const float*)d_in[9];
    const float* Wnbr  = (const float*)d_in[10];
    const float* bnbr  = (const float*)d_in[11];
    const float* Wih_d = (const float*)d_in[12];
    const float* Whh_d = (const float*)d_in[13];
    const float* bih_d = (const float*)d_in[14];
    const float* bhh_d = (const float*)d_in[15];
    const float* Wop   = (const float*)d_in[16];
    const float* bop   = (const float*)d_in[17];
    const int*   seg   = (const int*)d_in[18];
    float* fut = (float*)d_out;

    hipLaunchKernelGGL(highway_fused, dim3(BHERO / 16), dim3(512), 0, stream,
                       hist, nbrs, Wip, bip, Wih_e, Whh_e, bih_e, bhh_e, Wdyn, bdyn,
                       Wnbr, bnbr, Wih_d, Whh_d, bih_d, bhh_d, Wop, bop, seg, fut);
}